// Round 14
// baseline (244.570 us; speedup 1.0000x reference)
//
#include <hip/hip_runtime.h>

// Problem constants: B=8, C=4, H=W=512, K_ITERS=10, ALPHA=2
#define Wd   512
#define W4   128
#define W8   64
#define HWp  262144
#define NTOT 8388608

#define NBP  16               // blocks per plane (persistent path)
#define RPW  7                // rows per wave (8 waves cover 56 >= 52)

#define F_INF __int_as_float(0x7F800000)

typedef _Float16 half8 __attribute__((ext_vector_type(8)));
typedef _Float16 half4v __attribute__((ext_vector_type(4)));

// red[] layout (floats, zero-init; min slots store ~bits so 0 = identity):
//   gmn[gs][c][p] = red[(gs*3+c)*32+p]          gs=0..9 (stats of g_{gs+1}), c=cnt-3
//   gmx[gs][c][p] = red[960 + (gs*3+c)*32+p]
//   sum[kk][p]    = red[1920 + kk*32 + p]       raw-x sums, pass kk+1
// pcnt: (gs*32+plane)*16 arrival counters; done: final counter.

// ---------------------------------------------------------------- helpers

__device__ __forceinline__ float4 bound4(const float* __restrict__ pred,
                                         const int* __restrict__ target,
                                         int plane, int v)
{
    const int b = plane >> 2, c = plane & 3;
    float4 p = ((const float4*)(pred + (size_t)plane * HWp))[v];
    int4   t = ((const int4*)(target + (size_t)b * HWp))[v];
    float dx = p.x - (t.x == c ? 1.0f : 0.0f);
    float dy = p.y - (t.y == c ? 1.0f : 0.0f);
    float dz = p.z - (t.z == c ? 1.0f : 0.0f);
    float dw = p.w - (t.w == c ? 1.0f : 0.0f);
    return make_float4(dx*dx, dy*dy, dz*dz, dw*dw);
}

__device__ __forceinline__ float bound1(const float* __restrict__ pred,
                                        const int* __restrict__ target,
                                        int plane, int i)
{
    const int b = plane >> 2, c = plane & 3;
    float p = pred[(size_t)plane * HWp + i];
    int   t = target[(size_t)b * HWp + i];
    float d = p - (t == c ? 1.0f : 0.0f);
    return d * d;
}

template <int NW>
__device__ __forceinline__ void block_reduce_commit(float lmin, float lmax,
                                                    float lsum,
                                                    float* __restrict__ red,
                                                    int k, int plane)
{
    for (int off = 32; off > 0; off >>= 1) {
        lmin = fminf(lmin, __shfl_down(lmin, off));
        lmax = fmaxf(lmax, __shfl_down(lmax, off));
        lsum += __shfl_down(lsum, off);
    }
    __shared__ float smin[NW], smax[NW], ssum[NW];
    const int wave = threadIdx.x >> 6;
    if ((threadIdx.x & 63) == 0) { smin[wave] = lmin; smax[wave] = lmax; ssum[wave] = lsum; }
    __syncthreads();
    if (threadIdx.x == 0) {
        float bmin = smin[0], bmax = smax[0], bsum = ssum[0];
        #pragma unroll
        for (int i = 1; i < NW; i++) {
            bmin = fminf(bmin, smin[i]);
            bmax = fmaxf(bmax, smax[i]);
            bsum += ssum[i];
        }
        atomicMax((unsigned*)&red[k * 32 + plane], ~__float_as_uint(bmin));
        atomicMax((int*)&red[320 + k * 32 + plane], __float_as_int(bmax));
        atomicAdd(&red[640 + k * 32 + plane], bsum);
    }
}

// =============== persistent register-resident pipelined path ===============
// 512 blocks (16/plane) x 512 threads. State: 7 rows/thread in registers.
// Per iter r: APPLY x_r = relu(affine(g_r)) [regs] -> publish 2 boundary
// rows -> sync -> GATHER g_{r+1} [regs + 2 shuffles/row, NO ds_read] with
// per-cnt-class gmin/gmax -> commit+arrive(r) -> spin(r-1) [arrived one
// full iteration ago -> propagation hidden].
__global__ __launch_bounds__(512) void hausdorff_reg(
    const float* __restrict__ pred, const int* __restrict__ target,
    float* __restrict__ out, float* __restrict__ red,
    unsigned* __restrict__ pcnt, unsigned* __restrict__ done)
{
    const int bid   = blockIdx.x;
    const int plane = bid >> 4, binp = bid & 15;
    const int A     = binp * 32;
    const int rl    = (A - 10 < 0) ? 0 : A - 10;
    const int rh    = (A + 42 > Wd) ? Wd : A + 42;
    const int tid   = threadIdx.x, lane = tid & 63, w = tid >> 6;
    const int s0r   = rl + w * RPW;            // wave band: rows s0r..s0r+6

    __shared__ _Float16 exT[8][Wd], exB[8][Wd];   // wave boundary exchange
    __shared__ float rs[8][7];
    __shared__ float bcs[2];

    half8 st[RPW];                             // row state (x or g)
    float s = 1.0f, o = 0.0f;
    float gmn[3], gmx[3];
    float xsum = 0.0f;

    // ---- stage x_0 = (pred - onehot)^2 directly into registers ----
    {
        const int cc = plane & 3;
        const float* pp = pred   + (size_t)plane * HWp;
        const int*   tp = target + (size_t)(plane >> 2) * HWp;
        #pragma unroll
        for (int i = 0; i < RPW; i++) {
            const int r = s0r + i;
            half8 hv = (half8)(_Float16)0;
            if (r < rh) {
                const int base = r * Wd + lane * 8;
                float4 p0 = *(const float4*)(pp + base);
                float4 p1 = *(const float4*)(pp + base + 4);
                int4   t0 = *(const int4*)(tp + base);
                int4   t1 = *(const int4*)(tp + base + 4);
                float d;
                d = p0.x - (t0.x == cc ? 1.0f : 0.0f); hv[0] = (_Float16)(d*d);
                d = p0.y - (t0.y == cc ? 1.0f : 0.0f); hv[1] = (_Float16)(d*d);
                d = p0.z - (t0.z == cc ? 1.0f : 0.0f); hv[2] = (_Float16)(d*d);
                d = p0.w - (t0.w == cc ? 1.0f : 0.0f); hv[3] = (_Float16)(d*d);
                d = p1.x - (t1.x == cc ? 1.0f : 0.0f); hv[4] = (_Float16)(d*d);
                d = p1.y - (t1.y == cc ? 1.0f : 0.0f); hv[5] = (_Float16)(d*d);
                d = p1.z - (t1.z == cc ? 1.0f : 0.0f); hv[6] = (_Float16)(d*d);
                d = p1.w - (t1.w == cc ? 1.0f : 0.0f); hv[7] = (_Float16)(d*d);
            }
            st[i] = hv;
        }
    }

    auto publish = [&]() {
        ((half8*)&exT[w][0])[lane] = st[0];
        ((half8*)&exB[w][0])[lane] = st[RPW - 1];
    };

    // GATHER: st (x) -> st (g); class stats over owned rows.
    auto gather = [&](int m) {
        int lo = A - m;       if (lo < 0)  lo = 0;
        int hi = A + 32 + m;  if (hi > Wd) hi = Wd;
        gmn[0] = gmn[1] = gmn[2] = F_INF;
        gmx[0] = gmx[1] = gmx[2] = 0.0f;

        float fU[8], fC[8], fD[8];
        half8 up = (w > 0) ? ((const half8*)&exB[w - 1][0])[lane] : (half8)(_Float16)0;
        #pragma unroll
        for (int j = 0; j < 8; j++) { fU[j] = (float)up[j]; fC[j] = (float)st[0][j]; }

        #pragma unroll
        for (int i = 0; i < RPW; i++) {
            const int r = s0r + i;
            half8 dn;
            if (i < RPW - 1) dn = st[i + 1];
            else dn = (w < 7) ? ((const half8*)&exT[w + 1][0])[lane] : (half8)(_Float16)0;
            #pragma unroll
            for (int j = 0; j < 8; j++) fD[j] = (float)dn[j];
            if (r == 0) {
                for (int j = 0; j < 8; j++) fU[j] = 0.0f;
            }
            if (r == Wd - 1) {
                for (int j = 0; j < 8; j++) fD[j] = 0.0f;
            }

            if (r >= lo && r < hi) {               // wave-uniform mask
                float lft = __shfl_up(fC[7], 1);
                float rgt = __shfl_down(fC[0], 1);
                if (lane == 0)  lft = 0.0f;
                if (lane == 63) rgt = 0.0f;

                float gr[8];
                half8 gh;
                {
                    float g0 = fC[0] + lft + fC[1] + fU[0] + fD[0];
                    gh[0] = (_Float16)g0;
                }
                #pragma unroll
                for (int j = 1; j < 7; j++) {
                    float g = fC[j - 1] + fC[j] + fC[j + 1] + fU[j] + fD[j];
                    gh[j] = (_Float16)g;
                }
                {
                    float g7 = fC[6] + fC[7] + rgt + fU[7] + fD[7];
                    gh[7] = (_Float16)g7;
                }
                #pragma unroll
                for (int j = 0; j < 8; j++) gr[j] = (float)gh[j];
                st[i] = gh;

                if (r >= A && r < A + 32) {        // stats: owned rows only
                    // interior-col pixels j=1..6 are class (3+vc); lane-edge
                    // pixels (lane0,j0)/(lane63,j7) are class (2+vc)
                    float mI = fminf(fminf(fminf(gr[1], gr[2]), fminf(gr[3], gr[4])),
                                     fminf(gr[5], gr[6]));
                    float MI = fmaxf(fmaxf(fmaxf(gr[1], gr[2]), fmaxf(gr[3], gr[4])),
                                     fmaxf(gr[5], gr[6]));
                    float mE = F_INF, ME = 0.0f;
                    if (lane == 0) { mE = gr[0]; ME = gr[0]; }
                    else           { mI = fminf(mI, gr[0]); MI = fmaxf(MI, gr[0]); }
                    if (lane == 63) { mE = fminf(mE, gr[7]); ME = fmaxf(ME, gr[7]); }
                    else            { mI = fminf(mI, gr[7]); MI = fmaxf(MI, gr[7]); }
                    const int vc = ((r > 0) ? 1 : 0) + ((r < Wd - 1) ? 1 : 0);
                    if (vc == 2) {                 // interior row: classes 5,4
                        gmn[2] = fminf(gmn[2], mI); gmx[2] = fmaxf(gmx[2], MI);
                        gmn[1] = fminf(gmn[1], mE); gmx[1] = fmaxf(gmx[1], ME);
                    } else {                       // plane-edge row: classes 4,3
                        gmn[1] = fminf(gmn[1], mI); gmx[1] = fmaxf(gmx[1], MI);
                        gmn[0] = fminf(gmn[0], mE); gmx[0] = fmaxf(gmx[0], ME);
                    }
                }
            }
            #pragma unroll
            for (int j = 0; j < 8; j++) { fU[j] = fC[j]; fC[j] = fD[j]; }
        }
    };

    // APPLY: st (g) -> st (x) = relu(0.2*(s*g + o*cnt) - 0.5); sum over owned.
    auto apply = [&](int m) {
        int lo = A - m;       if (lo < 0)  lo = 0;
        int hi = A + 32 + m;  if (hi > Wd) hi = Wd;
        xsum = 0.0f;
        #pragma unroll
        for (int i = 0; i < RPW; i++) {
            const int r = s0r + i;
            if (r >= lo && r < hi) {
                const float vcf = (float)(((r > 0) ? 1 : 0) + ((r < Wd - 1) ? 1 : 0));
                half8 gh = st[i], eh;
                #pragma unroll
                for (int j = 0; j < 8; j++) {
                    float g = (float)gh[j];
                    const bool hl = (j > 0) || (lane > 0);
                    const bool hr = (j < 7) || (lane < 63);
                    float cnt = 1.0f + (hl ? 1.0f : 0.0f) + (hr ? 1.0f : 0.0f) + vcf;
                    float e = fmaxf(0.2f * (s * g + o * cnt) - 0.5f, 0.0f);
                    eh[j] = (_Float16)e;
                }
                st[i] = eh;
                if (r >= A && r < A + 32) {
                    #pragma unroll
                    for (int j = 0; j < 8; j++) xsum += (float)eh[j];
                }
            }
        }
    };

    // reduce 6 class stats + sum; commit to slot gs; arrive ctr[gs].
    auto reduce_commit = [&](int gs, int sumslot, bool dosum) {
        float v[7] = { gmn[0], gmn[1], gmn[2], gmx[0], gmx[1], gmx[2], xsum };
        for (int off = 32; off > 0; off >>= 1) {
            v[0] = fminf(v[0], __shfl_down(v[0], off));
            v[1] = fminf(v[1], __shfl_down(v[1], off));
            v[2] = fminf(v[2], __shfl_down(v[2], off));
            v[3] = fmaxf(v[3], __shfl_down(v[3], off));
            v[4] = fmaxf(v[4], __shfl_down(v[4], off));
            v[5] = fmaxf(v[5], __shfl_down(v[5], off));
            v[6] += __shfl_down(v[6], off);
        }
        if (lane == 0) {
            #pragma unroll
            for (int q = 0; q < 7; q++) rs[w][q] = v[q];
        }
        __syncthreads();
        if (tid == 0) {
            float a0 = rs[0][0], a1 = rs[0][1], a2 = rs[0][2];
            float a3 = rs[0][3], a4 = rs[0][4], a5 = rs[0][5], a6 = rs[0][6];
            #pragma unroll
            for (int q = 1; q < 8; q++) {
                a0 = fminf(a0, rs[q][0]); a1 = fminf(a1, rs[q][1]); a2 = fminf(a2, rs[q][2]);
                a3 = fmaxf(a3, rs[q][3]); a4 = fmaxf(a4, rs[q][4]); a5 = fmaxf(a5, rs[q][5]);
                a6 += rs[q][6];
            }
            atomicMax((unsigned*)&red[(gs * 3 + 0) * 32 + plane], ~__float_as_uint(a0));
            atomicMax((unsigned*)&red[(gs * 3 + 1) * 32 + plane], ~__float_as_uint(a1));
            atomicMax((unsigned*)&red[(gs * 3 + 2) * 32 + plane], ~__float_as_uint(a2));
            atomicMax((int*)&red[960 + (gs * 3 + 0) * 32 + plane], __float_as_int(a3));
            atomicMax((int*)&red[960 + (gs * 3 + 1) * 32 + plane], __float_as_int(a4));
            atomicMax((int*)&red[960 + (gs * 3 + 2) * 32 + plane], __float_as_int(a5));
            if (dosum) atomicAdd(&red[1920 + sumslot * 32 + plane], a6);
            __threadfence();
            atomicAdd(&pcnt[(gs * 32 + plane) * 16], 1u);
        }
    };

    // spin for gstats slot gs; derive (s,o) by the monotone-class recursion.
    auto spin_derive = [&](int gs) {
        if (tid == 0) {
            unsigned* ctr = &pcnt[(gs * 32 + plane) * 16];
            unsigned it = 0;
            while (__hip_atomic_load(ctr, __ATOMIC_RELAXED,
                                     __HIP_MEMORY_SCOPE_AGENT) < (unsigned)NBP) {
                __builtin_amdgcn_s_sleep(1);
                if (++it > (1u << 25)) break;
            }
            __threadfence();
            float mn = F_INF, mx = 0.0f;
            #pragma unroll
            for (int cc = 0; cc < 3; cc++) {
                float gn = __uint_as_float(~((volatile unsigned*)red)[(gs * 3 + cc) * 32 + plane]);
                float gx = ((volatile float*)red)[960 + (gs * 3 + cc) * 32 + plane];
                float cf = (float)(cc + 3);
                mn = fminf(mn, fmaxf(0.2f * (s * gn + o * cf) - 0.5f, 0.0f));
                mx = fmaxf(mx, fmaxf(0.2f * (s * gx + o * cf) - 0.5f, 0.0f));
            }
            float denom = mx - mn;
            float ns = 1.0f, no = 0.0f;
            if (denom != 0.0f) { ns = 1.0f / denom; no = -mn / denom; }
            bcs[0] = ns; bcs[1] = no;
        }
        __syncthreads();
        s = bcs[0]; o = bcs[1];
    };

    // ---- prologue: publish x0, gather g1 (margin 9), arrive slot 0 ----
    publish();
    __syncthreads();
    gather(9);
    reduce_commit(0, 0, false);

    // ---- iters 1..9 ----
    for (int r = 1; r <= 9; r++) {
        spin_derive(r - 1);             // (s_r, o_r); arrived last iter
        apply(10 - r);                  // x_r from g_r
        publish();
        __syncthreads();
        gather(9 - r);                  // g_{r+1}
        reduce_commit(r, r - 1, true);  // gstats slot r, sum of pass r
    }

    // ---- iter 10: derive (s_9,o_9), apply + sum only ----
    spin_derive(9);
    apply(0);
    {
        float v = xsum;
        for (int off = 32; off > 0; off >>= 1) v += __shfl_down(v, off);
        if (lane == 0) rs[w][0] = v;
        __syncthreads();
        if (tid == 0) {
            float sv = rs[0][0];
            #pragma unroll
            for (int q = 1; q < 8; q++) sv += rs[q][0];
            atomicAdd(&red[1920 + 9 * 32 + plane], sv);
            __threadfence();
            atomicAdd(done, 1u);
        }
    }

    // ---- epilogue: block 0 folds everything into the loss ----
    if (bid != 0) return;
    if (tid == 0) {
        unsigned it = 0;
        while (__hip_atomic_load(done, __ATOMIC_RELAXED,
                                 __HIP_MEMORY_SCOPE_AGENT) < 512u) {
            __builtin_amdgcn_s_sleep(1);
            if (++it > (1u << 25)) break;
        }
        __threadfence();
    }
    __syncthreads();
    if (tid < 64) {
        float contrib = 0.0f;
        if (tid < 32) {
            const int p = tid;
            float ss = 1.0f, oo = 0.0f;
            #pragma unroll
            for (int kk = 0; kk < 10; kk++) {
                float mn = F_INF, mx = 0.0f;
                #pragma unroll
                for (int cc = 0; cc < 3; cc++) {
                    float gn = __uint_as_float(~((volatile unsigned*)red)[(kk * 3 + cc) * 32 + p]);
                    float gx = ((volatile float*)red)[960 + (kk * 3 + cc) * 32 + p];
                    float cf = (float)(cc + 3);
                    mn = fminf(mn, fmaxf(0.2f * (ss * gn + oo * cf) - 0.5f, 0.0f));
                    mx = fmaxf(mx, fmaxf(0.2f * (ss * gx + oo * cf) - 0.5f, 0.0f));
                }
                float denom = mx - mn;
                float ns = 1.0f, no = 0.0f;
                if (denom != 0.0f) { ns = 1.0f / denom; no = -mn / denom; }
                float sm = ((volatile float*)red)[1920 + kk * 32 + p];
                contrib += (ns * sm + no * 262144.0f) * (float)((kk + 1) * (kk + 1));
                ss = ns; oo = no;
            }
        }
        for (int off = 16; off > 0; off >>= 1)
            contrib += __shfl_down(contrib, off);
        if (tid == 0) out[0] = contrib / 8388608.0f;
    }
}

// ===================== fallback: R10 multi-launch path =====================

__global__ __launch_bounds__(256) void stencil_first(const float* __restrict__ pred,
                                                     const int* __restrict__ target,
                                                     _Float16* __restrict__ out,
                                                     float* __restrict__ red)
{
    const int plane = blockIdx.y;
    const int chunk = blockIdx.x;

    _Float16* op = out + (size_t)plane * HWp;

    const int col4 = threadIdx.x & 127;
    const int rsub = threadIdx.x >> 7;

    float lmin = F_INF, lmax = 0.0f, lsum = 0.0f;
    const bool hasL = (col4 > 0);
    const bool hasR = (col4 < W4 - 1);

    #pragma unroll
    for (int p = 0; p < 8; p++) {
        const int row = chunk * 16 + p * 2 + rsub;
        const int v   = row * W4 + col4;
        const bool hasU = (row > 0);
        const bool hasD = (row < Wd - 1);

        float4 c4 = bound4(pred, target, plane, v);
        float4 u4 = hasU ? bound4(pred, target, plane, v - W4) : make_float4(0,0,0,0);
        float4 d4 = hasD ? bound4(pred, target, plane, v + W4) : make_float4(0,0,0,0);
        float lft = hasL ? bound1(pred, target, plane, 4*v - 1) : 0.0f;
        float rgt = hasR ? bound1(pred, target, plane, 4*v + 4) : 0.0f;

        float4 sum;
        sum.x = c4.x + c4.y + u4.x + d4.x + lft;
        sum.y = c4.x + c4.y + c4.z + u4.y + d4.y;
        sum.z = c4.y + c4.z + c4.w + u4.z + d4.z;
        sum.w = c4.z + c4.w + rgt + u4.w + d4.w;

        float4 e;
        e.x = fmaxf(0.2f * sum.x - 0.5f, 0.0f);
        e.y = fmaxf(0.2f * sum.y - 0.5f, 0.0f);
        e.z = fmaxf(0.2f * sum.z - 0.5f, 0.0f);
        e.w = fmaxf(0.2f * sum.w - 0.5f, 0.0f);

        half4v h;
        h[0] = (_Float16)e.x; h[1] = (_Float16)e.y;
        h[2] = (_Float16)e.z; h[3] = (_Float16)e.w;
        ((half4v*)op)[v] = h;

        float r0 = (float)h[0], r1 = (float)h[1], r2 = (float)h[2], r3 = (float)h[3];
        lmin = fminf(lmin, fminf(fminf(r0, r1), fminf(r2, r3)));
        lmax = fmaxf(lmax, fmaxf(fmaxf(r0, r1), fmaxf(r2, r3)));
        lsum += (r0 + r1) + (r2 + r3);
    }

    block_reduce_commit<4>(lmin, lmax, lsum, red, 0, plane);
}

__global__ __launch_bounds__(512) void stencil_h(const _Float16* __restrict__ in,
                                                 _Float16* __restrict__ out,
                                                 float* __restrict__ red,
                                                 int k, int store)
{
    const int plane = blockIdx.y;
    const int chunk = blockIdx.x;

    float mn = __uint_as_float(~((const unsigned*)red)[(k - 1) * 32 + plane]);
    float mx = red[320 + (k - 1) * 32 + plane];
    float denom = mx - mn;
    float s = 1.0f, o = 0.0f;
    if (denom != 0.0f) { s = 1.0f / denom; o = -mn / denom; }

    const _Float16* ip = in  + (size_t)plane * HWp;
    _Float16*       op = out + (size_t)plane * HWp;

    const int col8 = threadIdx.x & 63;
    const int wv   = threadIdx.x >> 6;
    const int r0   = chunk * 16 + wv * 2;
    const int v0   = r0 * W8 + col8;

    const bool hasL  = (col8 > 0);
    const bool hasR  = (col8 < W8 - 1);
    const bool hasU0 = (r0 > 0);
    const bool hasD1 = (r0 + 2 < Wd);

    half8 u8 = hasU0 ? ((const half8*)ip)[v0 - W8]     : (half8)(_Float16)0;
    half8 c0 = ((const half8*)ip)[v0];
    half8 c1 = ((const half8*)ip)[v0 + W8];
    half8 d8 = hasD1 ? ((const half8*)ip)[v0 + 2 * W8] : (half8)(_Float16)0;

    float uf[8], f0[8], f1[8], df[8];
    #pragma unroll
    for (int j = 0; j < 8; j++) {
        uf[j] = (float)u8[j];
        f0[j] = (float)c0[j]; f1[j] = (float)c1[j];
        df[j] = (float)d8[j];
    }

    float lmin = F_INF, lmax = 0.0f, lsum = 0.0f;

    auto PROC = [&](const float* up, const float* cen, const float* dn, int row) {
        const bool hasU = (row > 0);
        const bool hasD = (row < Wd - 1);
        float lft = __shfl_up(cen[7], 1);
        float rgt = __shfl_down(cen[0], 1);
        if (!hasL) lft = 0.0f;
        if (!hasR) rgt = 0.0f;

        const float vc = (hasU ? 1.0f : 0.0f) + (hasD ? 1.0f : 0.0f);
        half8 eh;
        #pragma unroll
        for (int j = 0; j < 8; j++) {
            const float lnb = (j == 0) ? lft : cen[j - 1];
            const float rnb = (j == 7) ? rgt : cen[j + 1];
            const bool  hl  = (j > 0) || hasL;
            const bool  hr  = (j < 7) || hasR;
            float sum = cen[j] + lnb + rnb + up[j] + dn[j];
            float cnt = 1.0f + (hl ? 1.0f : 0.0f) + (hr ? 1.0f : 0.0f) + vc;
            float e = fmaxf(0.2f * (s * sum + o * cnt) - 0.5f, 0.0f);
            _Float16 h = (_Float16)e;
            eh[j] = h;
            float er = (float)h;
            lmin = fminf(lmin, er);
            lmax = fmaxf(lmax, er);
            lsum += er;
        }
        if (store) ((half8*)op)[row * W8 + col8] = eh;
    };

    PROC(uf, f0, f1, r0);
    PROC(f0, f1, df, r0 + 1);

    block_reduce_commit<8>(lmin, lmax, lsum, red, k, plane);
}

__global__ void final_out(const float* __restrict__ red, float* __restrict__ out)
{
    const int lane = threadIdx.x;
    float contrib = 0.0f;
    if (lane < 32) {
        #pragma unroll
        for (int kk = 0; kk < 10; kk++) {
            float mn = __uint_as_float(~((const unsigned*)red)[kk * 32 + lane]);
            float mx = red[320 + kk * 32 + lane];
            float sm = red[640 + kk * 32 + lane];
            float denom = mx - mn;
            float ss = 1.0f, oo = 0.0f;
            if (denom != 0.0f) { ss = 1.0f / denom; oo = -mn / denom; }
            float w = (float)((kk + 1) * (kk + 1));
            contrib += (ss * sm + oo * 262144.0f) * w;
        }
    }
    for (int off = 16; off > 0; off >>= 1)
        contrib += __shfl_down(contrib, off);
    if (lane == 0) out[0] = contrib / 8388608.0f;
}

extern "C" void kernel_launch(void* const* d_in, const int* in_sizes, int n_in,
                              void* d_out, int out_size, void* d_ws, size_t ws_size,
                              hipStream_t stream)
{
    const float* pred   = (const float*)d_in[0];
    const int*   target = (const int*)d_in[1];
    float* out = (float*)d_out;

    _Float16* h0   = (_Float16*)d_ws;
    _Float16* h1   = h0 + NTOT;
    float*    red  = (float*)(h1 + NTOT);
    unsigned* pcnt = (unsigned*)(red + 2240);
    unsigned* done = pcnt + 5120;

    // zero gstats(1920) + sums(320) + pcnt(5120) + done
    hipMemsetAsync((void*)red, 0, (2240 + 5120 + 16) * 4, stream);

    static int persist_ok = -1;
    if (persist_ok < 0) {
        int bpc = 0, ncu = 0, dev = 0;
        hipError_t e1 = hipOccupancyMaxActiveBlocksPerMultiprocessor(
            &bpc, (const void*)hausdorff_reg, 512, 0);
        hipGetDevice(&dev);
        hipError_t e2 = hipDeviceGetAttribute(
            &ncu, hipDeviceAttributeMultiprocessorCount, dev);
        persist_ok = (e1 == hipSuccess && e2 == hipSuccess &&
                      bpc >= 2 && bpc * ncu >= 512) ? 1 : 0;
    }

    if (persist_ok) {
        void* args[] = { &pred, &target, &out, &red, &pcnt, &done };
        hipError_t e = hipLaunchCooperativeKernel(
            (void*)hausdorff_reg, dim3(512), dim3(512), args, 0, stream);
        if (e == hipSuccess) return;
    }

    // fallback: round-10-verified multi-launch pipeline (240.8 us)
    dim3 grid(32, 32);
    stencil_first<<<grid, 256, 0, stream>>>(pred, target, h0, red);
    const _Float16* a = h0;
    _Float16*       b = h1;
    for (int k = 1; k < 10; k++) {
        stencil_h<<<grid, 512, 0, stream>>>(a, b, red, k, (k < 9) ? 1 : 0);
        const _Float16* t = a; a = b; b = (_Float16*)t;
    }
    final_out<<<1, 64, 0, stream>>>(red, out);
}

// Round 15
// 244.508 us; speedup vs baseline: 1.0003x; 1.0003x over previous
//
#include <hip/hip_runtime.h>

// Problem constants: B=8, C=4, H=W=512, K_ITERS=10, ALPHA=2
#define Wd   512
#define W4   128
#define W8   64
#define HWp  262144
#define NTOT 8388608

#define NBP  16               // blocks per plane (persistent path)
#define RPW  7                // rows per wave (8 waves cover 56 >= 52)

#define F_INF __int_as_float(0x7F800000)

typedef _Float16 half8 __attribute__((ext_vector_type(8)));
typedef _Float16 half4v __attribute__((ext_vector_type(4)));

// red[] layout (floats, zero-init; min slots store ~bits so 0 = identity):
//   gmn[gs][c][p] = red[(gs*3+c)*32+p]        gs=0..9 = class stats of g_{gs+1}
//   gmx[gs][c][p] = red[960 + (gs*3+c)*32+p]
//   sum[kk][p]    = red[1920 + kk*32 + p]     raw-x sums of pass kk+1
// pcnt: (gs*32+plane)*16 arrival counters; done: final counter.

__device__ __forceinline__ float4 bound4(const float* __restrict__ pred,
                                         const int* __restrict__ target,
                                         int plane, int v)
{
    const int b = plane >> 2, c = plane & 3;
    float4 p = ((const float4*)(pred + (size_t)plane * HWp))[v];
    int4   t = ((const int4*)(target + (size_t)b * HWp))[v];
    float dx = p.x - (t.x == c ? 1.0f : 0.0f);
    float dy = p.y - (t.y == c ? 1.0f : 0.0f);
    float dz = p.z - (t.z == c ? 1.0f : 0.0f);
    float dw = p.w - (t.w == c ? 1.0f : 0.0f);
    return make_float4(dx*dx, dy*dy, dz*dz, dw*dw);
}

__device__ __forceinline__ float bound1(const float* __restrict__ pred,
                                        const int* __restrict__ target,
                                        int plane, int i)
{
    const int b = plane >> 2, c = plane & 3;
    float p = pred[(size_t)plane * HWp + i];
    int   t = target[(size_t)b * HWp + i];
    float d = p - (t == c ? 1.0f : 0.0f);
    return d * d;
}

template <int NW>
__device__ __forceinline__ void block_reduce_commit(float lmin, float lmax,
                                                    float lsum,
                                                    float* __restrict__ red,
                                                    int k, int plane)
{
    for (int off = 32; off > 0; off >>= 1) {
        lmin = fminf(lmin, __shfl_down(lmin, off));
        lmax = fmaxf(lmax, __shfl_down(lmax, off));
        lsum += __shfl_down(lsum, off);
    }
    __shared__ float smin[NW], smax[NW], ssum[NW];
    const int wave = threadIdx.x >> 6;
    if ((threadIdx.x & 63) == 0) { smin[wave] = lmin; smax[wave] = lmax; ssum[wave] = lsum; }
    __syncthreads();
    if (threadIdx.x == 0) {
        float bmin = smin[0], bmax = smax[0], bsum = ssum[0];
        #pragma unroll
        for (int i = 1; i < NW; i++) {
            bmin = fminf(bmin, smin[i]);
            bmax = fmaxf(bmax, smax[i]);
            bsum += ssum[i];
        }
        atomicMax((unsigned*)&red[k * 32 + plane], ~__float_as_uint(bmin));
        atomicMax((int*)&red[320 + k * 32 + plane], __float_as_int(bmax));
        atomicAdd(&red[640 + k * 32 + plane], bsum);
    }
}

// ====== persistent register-resident path, packed-fp16 gather ======
// 512 blocks (16/plane) x 512 threads, 7 rows/thread in half8 registers.
// Iter k: apply_k (fp32 affine+relu, (s,o) derived LAST iter) -> publish
// band-boundary rows -> sync -> gather g_{k+1} in PACKED fp16 (v_pk_add,
// zero ds_read on critical path) + per-cnt-class g-extrema -> commit slot k
// -> spin slot k-1 (arrived one full iteration ago -> propagation hidden).
__global__ __launch_bounds__(512) void hausdorff_reg2(
    const float* __restrict__ pred, const int* __restrict__ target,
    float* __restrict__ out, float* __restrict__ red,
    unsigned* __restrict__ pcnt, unsigned* __restrict__ done)
{
    const int bid   = blockIdx.x;
    const int plane = bid >> 4, binp = bid & 15;
    const int A     = binp * 32;
    const int rl    = (A - 10 < 0) ? 0 : A - 10;
    const int rh    = (A + 42 > Wd) ? Wd : A + 42;
    const int tid   = threadIdx.x, lane = tid & 63, w = tid >> 6;
    const int s0r   = rl + w * RPW;            // wave band rows s0r..s0r+6

    __shared__ _Float16 exT[8][Wd], exB[8][Wd];   // band-boundary exchange
    __shared__ float rs[8][7];
    __shared__ float bcs[2];

    half8 st[RPW];                             // row state (x or g), 28 VGPR
    float s = 1.0f, o = 0.0f;
    float gmn[3], gmx[3];
    float xsum = 0.0f;
    const half8 z8 = (half8)(_Float16)0;

    // ---- stage x_0 = (pred - onehot)^2 directly into registers ----
    {
        const int cc = plane & 3;
        const float* pp = pred   + (size_t)plane * HWp;
        const int*   tp = target + (size_t)(plane >> 2) * HWp;
        #pragma unroll
        for (int i = 0; i < RPW; i++) {
            const int r = s0r + i;
            half8 hv = z8;
            if (r < rh) {
                const int base = r * Wd + lane * 8;
                float4 p0 = *(const float4*)(pp + base);
                float4 p1 = *(const float4*)(pp + base + 4);
                int4   t0 = *(const int4*)(tp + base);
                int4   t1 = *(const int4*)(tp + base + 4);
                float d;
                d = p0.x - (t0.x == cc ? 1.0f : 0.0f); hv[0] = (_Float16)(d*d);
                d = p0.y - (t0.y == cc ? 1.0f : 0.0f); hv[1] = (_Float16)(d*d);
                d = p0.z - (t0.z == cc ? 1.0f : 0.0f); hv[2] = (_Float16)(d*d);
                d = p0.w - (t0.w == cc ? 1.0f : 0.0f); hv[3] = (_Float16)(d*d);
                d = p1.x - (t1.x == cc ? 1.0f : 0.0f); hv[4] = (_Float16)(d*d);
                d = p1.y - (t1.y == cc ? 1.0f : 0.0f); hv[5] = (_Float16)(d*d);
                d = p1.z - (t1.z == cc ? 1.0f : 0.0f); hv[6] = (_Float16)(d*d);
                d = p1.w - (t1.w == cc ? 1.0f : 0.0f); hv[7] = (_Float16)(d*d);
            }
            st[i] = hv;
        }
    }

    auto publish = [&]() {
        ((half8*)&exT[w][0])[lane] = st[0];
        ((half8*)&exB[w][0])[lane] = st[RPW - 1];
    };

    // GATHER (packed fp16): st (x) -> st (g); per-class extrema, owned rows.
    auto gather = [&](int m) {
        int lo = A - m;       if (lo < 0)  lo = 0;
        int hi = A + 32 + m;  if (hi > Wd) hi = Wd;
        gmn[0] = gmn[1] = gmn[2] = F_INF;
        gmx[0] = gmx[1] = gmx[2] = 0.0f;

        half8 up  = (w > 0) ? ((const half8*)&exB[w - 1][0])[lane] : z8;
        half8 cur = st[0];
        #pragma unroll
        for (int i = 0; i < RPW; i++) {
            const int r = s0r + i;
            half8 dn;
            if (i < RPW - 1) dn = st[i + 1];
            else             dn = (w < 7) ? ((const half8*)&exT[w + 1][0])[lane] : z8;
            const half8 u8 = (r == 0)      ? z8 : up;
            const half8 d8 = (r == Wd - 1) ? z8 : dn;

            if (r >= lo && r < hi) {               // wave-uniform branch
                float c7f = (float)cur[7], c0f = (float)cur[0];
                float lftf = __shfl_up(c7f, 1);
                float rgtf = __shfl_down(c0f, 1);
                half8 ls, rv;
                ls[0] = (lane == 0)  ? (_Float16)0 : (_Float16)lftf;
                rv[7] = (lane == 63) ? (_Float16)0 : (_Float16)rgtf;
                #pragma unroll
                for (int j = 1; j < 8; j++) ls[j] = cur[j - 1];
                #pragma unroll
                for (int j = 0; j < 7; j++) rv[j] = cur[j + 1];

                half8 g = cur + ls + rv + u8 + d8;  // v_pk_add_f16 chain
                st[i] = g;

                if (r >= A && r < A + 32) {         // stats: owned rows only
                    float gf[8];
                    #pragma unroll
                    for (int j = 0; j < 8; j++) gf[j] = (float)g[j];
                    float mI = fminf(fminf(fminf(gf[1], gf[2]), fminf(gf[3], gf[4])),
                                     fminf(gf[5], gf[6]));
                    float MI = fmaxf(fmaxf(fmaxf(gf[1], gf[2]), fmaxf(gf[3], gf[4])),
                                     fmaxf(gf[5], gf[6]));
                    float mE = F_INF, ME = 0.0f;
                    if (lane == 0) { mE = gf[0]; ME = gf[0]; }
                    else           { mI = fminf(mI, gf[0]); MI = fmaxf(MI, gf[0]); }
                    if (lane == 63) { mE = fminf(mE, gf[7]); ME = fmaxf(ME, gf[7]); }
                    else            { mI = fminf(mI, gf[7]); MI = fmaxf(MI, gf[7]); }
                    const int vc = ((r > 0) ? 1 : 0) + ((r < Wd - 1) ? 1 : 0);
                    if (vc == 2) {                  // interior row: classes 5,4
                        gmn[2] = fminf(gmn[2], mI); gmx[2] = fmaxf(gmx[2], MI);
                        gmn[1] = fminf(gmn[1], mE); gmx[1] = fmaxf(gmx[1], ME);
                    } else {                        // plane-edge row: classes 4,3
                        gmn[1] = fminf(gmn[1], mI); gmx[1] = fmaxf(gmx[1], MI);
                        gmn[0] = fminf(gmn[0], mE); gmx[0] = fmaxf(gmx[0], ME);
                    }
                }
            }
            up = cur; cur = dn;                     // roll (pre-overwrite x)
        }
    };

    // APPLY: st (g) -> st (x) = relu(0.2*(s*g + o*cnt) - 0.5); sum over owned.
    auto apply = [&](int m) {
        int lo = A - m;       if (lo < 0)  lo = 0;
        int hi = A + 32 + m;  if (hi > Wd) hi = Wd;
        xsum = 0.0f;
        #pragma unroll
        for (int i = 0; i < RPW; i++) {
            const int r = s0r + i;
            if (r >= lo && r < hi) {
                const float vcf = (float)(((r > 0) ? 1 : 0) + ((r < Wd - 1) ? 1 : 0));
                half8 gh = st[i], eh;
                #pragma unroll
                for (int j = 0; j < 8; j++) {
                    float g = (float)gh[j];
                    const bool hl = (j > 0) || (lane > 0);
                    const bool hr = (j < 7) || (lane < 63);
                    float cnt = 1.0f + (hl ? 1.0f : 0.0f) + (hr ? 1.0f : 0.0f) + vcf;
                    float e = fmaxf(0.2f * (s * g + o * cnt) - 0.5f, 0.0f);
                    eh[j] = (_Float16)e;
                }
                st[i] = eh;
                if (r >= A && r < A + 32) {
                    #pragma unroll
                    for (int j = 0; j < 8; j++) xsum += (float)eh[j];
                }
            }
        }
    };

    auto reduce_commit = [&](int gs, int sumslot, bool dosum) {
        float v[7] = { gmn[0], gmn[1], gmn[2], gmx[0], gmx[1], gmx[2], xsum };
        for (int off = 32; off > 0; off >>= 1) {
            v[0] = fminf(v[0], __shfl_down(v[0], off));
            v[1] = fminf(v[1], __shfl_down(v[1], off));
            v[2] = fminf(v[2], __shfl_down(v[2], off));
            v[3] = fmaxf(v[3], __shfl_down(v[3], off));
            v[4] = fmaxf(v[4], __shfl_down(v[4], off));
            v[5] = fmaxf(v[5], __shfl_down(v[5], off));
            v[6] += __shfl_down(v[6], off);
        }
        if (lane == 0) {
            #pragma unroll
            for (int q = 0; q < 7; q++) rs[w][q] = v[q];
        }
        __syncthreads();
        if (tid == 0) {
            float a0 = rs[0][0], a1 = rs[0][1], a2 = rs[0][2];
            float a3 = rs[0][3], a4 = rs[0][4], a5 = rs[0][5], a6 = rs[0][6];
            #pragma unroll
            for (int q = 1; q < 8; q++) {
                a0 = fminf(a0, rs[q][0]); a1 = fminf(a1, rs[q][1]); a2 = fminf(a2, rs[q][2]);
                a3 = fmaxf(a3, rs[q][3]); a4 = fmaxf(a4, rs[q][4]); a5 = fmaxf(a5, rs[q][5]);
                a6 += rs[q][6];
            }
            atomicMax((unsigned*)&red[(gs * 3 + 0) * 32 + plane], ~__float_as_uint(a0));
            atomicMax((unsigned*)&red[(gs * 3 + 1) * 32 + plane], ~__float_as_uint(a1));
            atomicMax((unsigned*)&red[(gs * 3 + 2) * 32 + plane], ~__float_as_uint(a2));
            atomicMax((int*)&red[960 + (gs * 3 + 0) * 32 + plane], __float_as_int(a3));
            atomicMax((int*)&red[960 + (gs * 3 + 1) * 32 + plane], __float_as_int(a4));
            atomicMax((int*)&red[960 + (gs * 3 + 2) * 32 + plane], __float_as_int(a5));
            if (dosum) atomicAdd(&red[1920 + sumslot * 32 + plane], a6);
            __threadfence();
            atomicAdd(&pcnt[(gs * 32 + plane) * 16], 1u);
        }
    };

    auto spin_derive = [&](int gs) {
        if (tid == 0) {
            unsigned* ctr = &pcnt[(gs * 32 + plane) * 16];
            unsigned it = 0;
            while (__hip_atomic_load(ctr, __ATOMIC_RELAXED,
                                     __HIP_MEMORY_SCOPE_AGENT) < (unsigned)NBP) {
                __builtin_amdgcn_s_sleep(1);
                if (++it > (1u << 25)) break;
            }
            __threadfence();
            float mn = F_INF, mx = 0.0f;
            #pragma unroll
            for (int cc = 0; cc < 3; cc++) {
                float gn = __uint_as_float(~((volatile unsigned*)red)[(gs * 3 + cc) * 32 + plane]);
                float gx = ((volatile float*)red)[960 + (gs * 3 + cc) * 32 + plane];
                float cf = (float)(cc + 3);
                mn = fminf(mn, fmaxf(0.2f * (s * gn + o * cf) - 0.5f, 0.0f));
                mx = fmaxf(mx, fmaxf(0.2f * (s * gx + o * cf) - 0.5f, 0.0f));
            }
            float denom = mx - mn;
            float ns = 1.0f, no = 0.0f;
            if (denom != 0.0f) { ns = 1.0f / denom; no = -mn / denom; }
            bcs[0] = ns; bcs[1] = no;
        }
        __syncthreads();
        s = bcs[0]; o = bcs[1];
    };

    // ---- prologue: publish x0, gather g1 (margin 9), commit slot 0 ----
    publish();
    __syncthreads();
    gather(9);
    reduce_commit(0, 0, false);

    // ---- iters 1..9: apply_k -> gather g_{k+1}+commit(k) -> spin(k-1) ----
    for (int k = 1; k <= 9; k++) {
        if (k > 1) { /* (s,o) for this apply derived at end of iter k-1 */ }
        apply(10 - k);
        publish();
        __syncthreads();
        gather(9 - k);
        reduce_commit(k, k - 1, true);  // slot k = g_{k+1} stats; sum of pass k
        spin_derive(k - 1);             // (s_k,o_k); slot k-1 arrived LAST iter
    }

    // ---- iter 10: apply + sum only ----
    apply(0);
    {
        float v = xsum;
        for (int off = 32; off > 0; off >>= 1) v += __shfl_down(v, off);
        if (lane == 0) rs[w][0] = v;
        __syncthreads();
        if (tid == 0) {
            float sv = rs[0][0];
            #pragma unroll
            for (int q = 1; q < 8; q++) sv += rs[q][0];
            atomicAdd(&red[1920 + 9 * 32 + plane], sv);
            __threadfence();
            atomicAdd(done, 1u);
        }
    }

    // ---- epilogue: block 0 folds everything into the loss ----
    if (bid != 0) return;
    if (tid == 0) {
        unsigned it = 0;
        while (__hip_atomic_load(done, __ATOMIC_RELAXED,
                                 __HIP_MEMORY_SCOPE_AGENT) < 512u) {
            __builtin_amdgcn_s_sleep(1);
            if (++it > (1u << 25)) break;
        }
        __threadfence();
    }
    __syncthreads();
    if (tid < 64) {
        float contrib = 0.0f;
        if (tid < 32) {
            const int p = tid;
            float ss = 1.0f, oo = 0.0f;
            #pragma unroll
            for (int kk = 0; kk < 10; kk++) {
                float mn = F_INF, mx = 0.0f;
                #pragma unroll
                for (int cc = 0; cc < 3; cc++) {
                    float gn = __uint_as_float(~((volatile unsigned*)red)[(kk * 3 + cc) * 32 + p]);
                    float gx = ((volatile float*)red)[960 + (kk * 3 + cc) * 32 + p];
                    float cf = (float)(cc + 3);
                    mn = fminf(mn, fmaxf(0.2f * (ss * gn + oo * cf) - 0.5f, 0.0f));
                    mx = fmaxf(mx, fmaxf(0.2f * (ss * gx + oo * cf) - 0.5f, 0.0f));
                }
                float denom = mx - mn;
                float ns = 1.0f, no = 0.0f;
                if (denom != 0.0f) { ns = 1.0f / denom; no = -mn / denom; }
                float sm = ((volatile float*)red)[1920 + kk * 32 + p];
                contrib += (ns * sm + no * 262144.0f) * (float)((kk + 1) * (kk + 1));
                ss = ns; oo = no;
            }
        }
        for (int off = 16; off > 0; off >>= 1)
            contrib += __shfl_down(contrib, off);
        if (tid == 0) out[0] = contrib / 8388608.0f;
    }
}

// ===================== fallback: R10 multi-launch path =====================

__global__ __launch_bounds__(256) void stencil_first(const float* __restrict__ pred,
                                                     const int* __restrict__ target,
                                                     _Float16* __restrict__ out,
                                                     float* __restrict__ red)
{
    const int plane = blockIdx.y;
    const int chunk = blockIdx.x;

    _Float16* op = out + (size_t)plane * HWp;

    const int col4 = threadIdx.x & 127;
    const int rsub = threadIdx.x >> 7;

    float lmin = F_INF, lmax = 0.0f, lsum = 0.0f;
    const bool hasL = (col4 > 0);
    const bool hasR = (col4 < W4 - 1);

    #pragma unroll
    for (int p = 0; p < 8; p++) {
        const int row = chunk * 16 + p * 2 + rsub;
        const int v   = row * W4 + col4;
        const bool hasU = (row > 0);
        const bool hasD = (row < Wd - 1);

        float4 c4 = bound4(pred, target, plane, v);
        float4 u4 = hasU ? bound4(pred, target, plane, v - W4) : make_float4(0,0,0,0);
        float4 d4 = hasD ? bound4(pred, target, plane, v + W4) : make_float4(0,0,0,0);
        float lft = hasL ? bound1(pred, target, plane, 4*v - 1) : 0.0f;
        float rgt = hasR ? bound1(pred, target, plane, 4*v + 4) : 0.0f;

        float4 sum;
        sum.x = c4.x + c4.y + u4.x + d4.x + lft;
        sum.y = c4.x + c4.y + c4.z + u4.y + d4.y;
        sum.z = c4.y + c4.z + c4.w + u4.z + d4.z;
        sum.w = c4.z + c4.w + rgt + u4.w + d4.w;

        float4 e;
        e.x = fmaxf(0.2f * sum.x - 0.5f, 0.0f);
        e.y = fmaxf(0.2f * sum.y - 0.5f, 0.0f);
        e.z = fmaxf(0.2f * sum.z - 0.5f, 0.0f);
        e.w = fmaxf(0.2f * sum.w - 0.5f, 0.0f);

        half4v h;
        h[0] = (_Float16)e.x; h[1] = (_Float16)e.y;
        h[2] = (_Float16)e.z; h[3] = (_Float16)e.w;
        ((half4v*)op)[v] = h;

        float r0 = (float)h[0], r1 = (float)h[1], r2 = (float)h[2], r3 = (float)h[3];
        lmin = fminf(lmin, fminf(fminf(r0, r1), fminf(r2, r3)));
        lmax = fmaxf(lmax, fmaxf(fmaxf(r0, r1), fmaxf(r2, r3)));
        lsum += (r0 + r1) + (r2 + r3);
    }

    block_reduce_commit<4>(lmin, lmax, lsum, red, 0, plane);
}

__global__ __launch_bounds__(512) void stencil_h(const _Float16* __restrict__ in,
                                                 _Float16* __restrict__ out,
                                                 float* __restrict__ red,
                                                 int k, int store)
{
    const int plane = blockIdx.y;
    const int chunk = blockIdx.x;

    float mn = __uint_as_float(~((const unsigned*)red)[(k - 1) * 32 + plane]);
    float mx = red[320 + (k - 1) * 32 + plane];
    float denom = mx - mn;
    float s = 1.0f, o = 0.0f;
    if (denom != 0.0f) { s = 1.0f / denom; o = -mn / denom; }

    const _Float16* ip = in  + (size_t)plane * HWp;
    _Float16*       op = out + (size_t)plane * HWp;

    const int col8 = threadIdx.x & 63;
    const int wv   = threadIdx.x >> 6;
    const int r0   = chunk * 16 + wv * 2;
    const int v0   = r0 * W8 + col8;

    const bool hasL  = (col8 > 0);
    const bool hasR  = (col8 < W8 - 1);
    const bool hasU0 = (r0 > 0);
    const bool hasD1 = (r0 + 2 < Wd);

    half8 u8 = hasU0 ? ((const half8*)ip)[v0 - W8]     : (half8)(_Float16)0;
    half8 c0 = ((const half8*)ip)[v0];
    half8 c1 = ((const half8*)ip)[v0 + W8];
    half8 d8 = hasD1 ? ((const half8*)ip)[v0 + 2 * W8] : (half8)(_Float16)0;

    float uf[8], f0[8], f1[8], df[8];
    #pragma unroll
    for (int j = 0; j < 8; j++) {
        uf[j] = (float)u8[j];
        f0[j] = (float)c0[j]; f1[j] = (float)c1[j];
        df[j] = (float)d8[j];
    }

    float lmin = F_INF, lmax = 0.0f, lsum = 0.0f;

    auto PROC = [&](const float* up, const float* cen, const float* dn, int row) {
        const bool hasU = (row > 0);
        const bool hasD = (row < Wd - 1);
        float lft = __shfl_up(cen[7], 1);
        float rgt = __shfl_down(cen[0], 1);
        if (!hasL) lft = 0.0f;
        if (!hasR) rgt = 0.0f;

        const float vc = (hasU ? 1.0f : 0.0f) + (hasD ? 1.0f : 0.0f);
        half8 eh;
        #pragma unroll
        for (int j = 0; j < 8; j++) {
            const float lnb = (j == 0) ? lft : cen[j - 1];
            const float rnb = (j == 7) ? rgt : cen[j + 1];
            const bool  hl  = (j > 0) || hasL;
            const bool  hr  = (j < 7) || hasR;
            float sum = cen[j] + lnb + rnb + up[j] + dn[j];
            float cnt = 1.0f + (hl ? 1.0f : 0.0f) + (hr ? 1.0f : 0.0f) + vc;
            float e = fmaxf(0.2f * (s * sum + o * cnt) - 0.5f, 0.0f);
            _Float16 h = (_Float16)e;
            eh[j] = h;
            float er = (float)h;
            lmin = fminf(lmin, er);
            lmax = fmaxf(lmax, er);
            lsum += er;
        }
        if (store) ((half8*)op)[row * W8 + col8] = eh;
    };

    PROC(uf, f0, f1, r0);
    PROC(f0, f1, df, r0 + 1);

    block_reduce_commit<8>(lmin, lmax, lsum, red, k, plane);
}

__global__ void final_out(const float* __restrict__ red, float* __restrict__ out)
{
    const int lane = threadIdx.x;
    float contrib = 0.0f;
    if (lane < 32) {
        #pragma unroll
        for (int kk = 0; kk < 10; kk++) {
            float mn = __uint_as_float(~((const unsigned*)red)[kk * 32 + lane]);
            float mx = red[320 + kk * 32 + lane];
            float sm = red[640 + kk * 32 + lane];
            float denom = mx - mn;
            float ss = 1.0f, oo = 0.0f;
            if (denom != 0.0f) { ss = 1.0f / denom; oo = -mn / denom; }
            float w = (float)((kk + 1) * (kk + 1));
            contrib += (ss * sm + oo * 262144.0f) * w;
        }
    }
    for (int off = 16; off > 0; off >>= 1)
        contrib += __shfl_down(contrib, off);
    if (lane == 0) out[0] = contrib / 8388608.0f;
}

extern "C" void kernel_launch(void* const* d_in, const int* in_sizes, int n_in,
                              void* d_out, int out_size, void* d_ws, size_t ws_size,
                              hipStream_t stream)
{
    const float* pred   = (const float*)d_in[0];
    const int*   target = (const int*)d_in[1];
    float* out = (float*)d_out;

    _Float16* h0   = (_Float16*)d_ws;
    _Float16* h1   = h0 + NTOT;
    float*    red  = (float*)(h1 + NTOT);
    unsigned* pcnt = (unsigned*)(red + 2240);
    unsigned* done = pcnt + 5120;

    // zero gstats(1920) + sums(320) + pcnt(5120) + done
    hipMemsetAsync((void*)red, 0, (2240 + 5120 + 16) * 4, stream);

    static int persist_ok = -1;
    if (persist_ok < 0) {
        int bpc = 0, ncu = 0, dev = 0;
        hipError_t e1 = hipOccupancyMaxActiveBlocksPerMultiprocessor(
            &bpc, (const void*)hausdorff_reg2, 512, 0);
        hipGetDevice(&dev);
        hipError_t e2 = hipDeviceGetAttribute(
            &ncu, hipDeviceAttributeMultiprocessorCount, dev);
        persist_ok = (e1 == hipSuccess && e2 == hipSuccess &&
                      bpc >= 2 && bpc * ncu >= 512) ? 1 : 0;
    }

    if (persist_ok) {
        void* args[] = { &pred, &target, &out, &red, &pcnt, &done };
        hipError_t e = hipLaunchCooperativeKernel(
            (void*)hausdorff_reg2, dim3(512), dim3(512), args, 0, stream);
        if (e == hipSuccess) return;
    }

    // fallback: round-10-verified multi-launch pipeline (240.8 us)
    dim3 grid(32, 32);
    stencil_first<<<grid, 256, 0, stream>>>(pred, target, h0, red);
    const _Float16* a = h0;
    _Float16*       b = h1;
    for (int k = 1; k < 10; k++) {
        stencil_h<<<grid, 512, 0, stream>>>(a, b, red, k, (k < 9) ? 1 : 0);
        const _Float16* t = a; a = b; b = (_Float16*)t;
    }
    final_out<<<1, 64, 0, stream>>>(red, out);
}

// Round 16
// 223.385 us; speedup vs baseline: 1.0948x; 1.0946x over previous
//
#include <hip/hip_runtime.h>

// Problem constants: B=8, C=4, H=W=512, K_ITERS=10, ALPHA=2
#define Wd   512
#define W8   64                // half8 granules per row
#define HWp  262144
#define NTOT 8388608

#define F_INF __int_as_float(0x7F800000)

typedef _Float16 half8 __attribute__((ext_vector_type(8)));

// red[] (per-plane stats, zero-init; mins stored as ~bits so 0 = identity):
//   gmn[i][c][p] = red[((i-1)*3+c)*32 + p]         i=1..10 (gather of pass i), c=cnt-3
//   gmx[i][c][p] = red[960 + ((i-1)*3+c)*32 + p]
//   sum[i][p]    = red[1920 + (i-1)*32 + p]        sum of un-normalized x~_i
//
// Key algebra: x~_i = round16(relu(0.2*(s_{i-1}*g~_i + o_{i-1}*cnt) - 0.5)) is
// per-cnt-class monotone in g~_i, so plane stats of x~_i (hence (s_i,o_i))
// derive EXACTLY from class extrema of g~_i + (s_{i-1},o_{i-1}).  A kernel
// that commits extrema of its last pass's g~ AND of a lookahead gather of its
// own output lets the NEXT kernel apply TWO passes -> 6 serial global
// round trips instead of 10 (the measured invariant cost, ~15us each).

// Derive (s_i,o_i) chain from red[]; record (s,o) pairs for i in
// [m0-1, m0+np-2] into sc[] (pass m0+p uses sc[2p],sc[2p+1]).
__device__ __forceinline__ void derive_chain(const float* __restrict__ red,
                                             int plane, int m0, int np,
                                             float* sc)
{
    float s = 1.0f, o = 0.0f;                  // (s_0, o_0)
    if (m0 == 1) { sc[0] = s; sc[1] = o; }
    const int upto = m0 + np - 2;
    for (int i = 1; i <= upto; i++) {
        float mn = F_INF, mx = 0.0f;
        #pragma unroll
        for (int c = 0; c < 3; c++) {
            float gn = __uint_as_float(~((const unsigned*)red)[((i-1)*3+c)*32 + plane]);
            float gx = red[960 + ((i-1)*3+c)*32 + plane];
            float cf = (float)(c + 3);
            float emn = (float)(_Float16)fmaxf(0.2f*(s*gn + o*cf) - 0.5f, 0.0f);
            float emx = (float)(_Float16)fmaxf(0.2f*(s*gx + o*cf) - 0.5f, 0.0f);
            mn = fminf(mn, emn);
            mx = fmaxf(mx, emx);
        }
        float denom = mx - mn;
        if (denom != 0.0f) { o = -mn / denom; s = 1.0f / denom; }
        else               { s = 1.0f;        o = 0.0f; }
        int idx = i - (m0 - 1);
        if (idx >= 0 && idx < np) { sc[2*idx] = s; sc[2*idx + 1] = o; }
    }
}

// One fused kernel: stages a 32+2*MIN row strip in LDS, applies NP passes
// with shrinking ghost margins (LDS-internal, no global sync), optionally a
// lookahead gather, then commits class extrema + sums.  16 blocks/plane x
// 32 planes = 512 blocks of 512 threads; plain multi-launch (no coop).
template<int NP, bool FIRST, bool LA, bool WRITE, int MIN>
__global__ __launch_bounds__(512) void fusedK(
    const _Float16* __restrict__ in, _Float16* __restrict__ out,
    const float* __restrict__ pred, const int* __restrict__ target,
    float* __restrict__ red, int m0)
{
    constexpr int TR = 32 + 2*MIN;                    // tile rows
    constexpr int NG = (32 + 2*(MIN-1) + 7) / 8;      // row groups per phase
    const int bid   = blockIdx.x;
    const int plane = bid >> 4, binp = bid & 15;
    const int A     = binp * 32;
    const int rlo   = (A - MIN < 0) ? 0 : A - MIN;
    const int rhi   = (A + 32 + MIN > Wd) ? Wd : A + 32 + MIN;
    const int tid   = threadIdx.x, lane = tid & 63, w = tid >> 6;

    __shared__ _Float16 tile[TR][Wd];
    __shared__ float scs[4];
    __shared__ float rsb[8][16];

    if (tid == 0) derive_chain(red, plane, m0, NP, scs);

    // ---- stage strip into LDS ----
    const int ngran = (rhi - rlo) * W8;
    if (FIRST) {
        const int cc = plane & 3;
        const float* pp = pred   + (size_t)plane * HWp;
        const int*   tp = target + (size_t)(plane >> 2) * HWp;
        for (int g = tid; g < ngran; g += 512) {
            const int lrow = g >> 6, lcol = g & 63;
            const int base = (rlo + lrow) * Wd + lcol * 8;
            float4 p0 = *(const float4*)(pp + base);
            float4 p1 = *(const float4*)(pp + base + 4);
            int4   t0 = *(const int4*)(tp + base);
            int4   t1 = *(const int4*)(tp + base + 4);
            half8 hv; float d;
            d = p0.x - (t0.x == cc ? 1.0f : 0.0f); hv[0] = (_Float16)(d*d);
            d = p0.y - (t0.y == cc ? 1.0f : 0.0f); hv[1] = (_Float16)(d*d);
            d = p0.z - (t0.z == cc ? 1.0f : 0.0f); hv[2] = (_Float16)(d*d);
            d = p0.w - (t0.w == cc ? 1.0f : 0.0f); hv[3] = (_Float16)(d*d);
            d = p1.x - (t1.x == cc ? 1.0f : 0.0f); hv[4] = (_Float16)(d*d);
            d = p1.y - (t1.y == cc ? 1.0f : 0.0f); hv[5] = (_Float16)(d*d);
            d = p1.z - (t1.z == cc ? 1.0f : 0.0f); hv[6] = (_Float16)(d*d);
            d = p1.w - (t1.w == cc ? 1.0f : 0.0f); hv[7] = (_Float16)(d*d);
            ((half8*)&tile[lrow][0])[lcol] = hv;
        }
    } else {
        const _Float16* ip = in + (size_t)plane * HWp;
        for (int g = tid; g < ngran; g += 512) {
            const int lrow = g >> 6, lcol = g & 63;
            ((half8*)&tile[lrow][0])[lcol] =
                ((const half8*)ip)[(rlo + lrow) * W8 + lcol];
        }
    }
    __syncthreads();

    half8 G[NG];
    float gmnL[3] = {F_INF, F_INF, F_INF}, gmxL[3] = {0.0f, 0.0f, 0.0f};
    float gmnA[3] = {F_INF, F_INF, F_INF}, gmxA[3] = {0.0f, 0.0f, 0.0f};
    float xsum[NP];

    // GATHER margin m: tile(x~) -> G(g~, fp16-rounded); class extrema (owned
    // rows) into gmn/gmx when acc.  Per-row class split (R13): interior-col
    // pixels are class vc, lane-edge pixels class vc-1 (vc = #vert nbrs).
    auto GATH = [&](int m, bool acc, float* gmn, float* gmx) {
        int lo = A - m;       if (lo < 0)  lo = 0;
        int hi = A + 32 + m;  if (hi > Wd) hi = Wd;
        #pragma unroll
        for (int gg = 0; gg < NG; gg++) {
            const int r = lo + gg * 8 + w;
            if (r < hi) {
                const int li = r - rlo;
                const half8 c8 = ((const half8*)&tile[li][0])[lane];
                half8 u8, d8;
                if (r > 0)      u8 = ((const half8*)&tile[li-1][0])[lane]; else u8 = (half8)(_Float16)0;
                if (r < Wd - 1) d8 = ((const half8*)&tile[li+1][0])[lane]; else d8 = (half8)(_Float16)0;
                const float lft = (lane > 0)  ? (float)tile[li][lane*8 - 1] : 0.0f;
                const float rgt = (lane < 63) ? (float)tile[li][lane*8 + 8] : 0.0f;
                float cf[8];
                #pragma unroll
                for (int j = 0; j < 8; j++) cf[j] = (float)c8[j];
                half8 gh;
                #pragma unroll
                for (int j = 0; j < 8; j++) {
                    const float ln = (j == 0) ? lft : cf[j - 1];
                    const float rn = (j == 7) ? rgt : cf[j + 1];
                    float gv = cf[j] + ln + rn + (float)u8[j] + (float)d8[j];
                    gh[j] = (_Float16)gv;
                }
                G[gg] = gh;
                if (acc && r >= A && r < A + 32) {
                    float gf[8];
                    #pragma unroll
                    for (int j = 0; j < 8; j++) gf[j] = (float)gh[j];
                    float mI = fminf(fminf(fminf(gf[1], gf[2]), fminf(gf[3], gf[4])),
                                     fminf(gf[5], gf[6]));
                    float MI = fmaxf(fmaxf(fmaxf(gf[1], gf[2]), fmaxf(gf[3], gf[4])),
                                     fmaxf(gf[5], gf[6]));
                    float mE = F_INF, ME = 0.0f;
                    if (lane == 0) { mE = gf[0]; ME = gf[0]; }
                    else           { mI = fminf(mI, gf[0]); MI = fmaxf(MI, gf[0]); }
                    if (lane == 63) { mE = fminf(mE, gf[7]); ME = fmaxf(ME, gf[7]); }
                    else            { mI = fminf(mI, gf[7]); MI = fmaxf(MI, gf[7]); }
                    const int vc = ((r > 0) ? 1 : 0) + ((r < Wd - 1) ? 1 : 0);
                    if (vc == 2) {               // interior row: classes 2,1
                        gmn[2] = fminf(gmn[2], mI); gmx[2] = fmaxf(gmx[2], MI);
                        gmn[1] = fminf(gmn[1], mE); gmx[1] = fmaxf(gmx[1], ME);
                    } else {                     // plane-edge row: classes 1,0
                        gmn[1] = fminf(gmn[1], mI); gmx[1] = fmaxf(gmx[1], MI);
                        gmn[0] = fminf(gmn[0], mE); gmx[0] = fmaxf(gmx[0], ME);
                    }
                }
            }
        }
    };

    // APPLY margin m: G(g~) -> tile(x~); sum (rounded) over owned rows.
    auto APP = [&](int m, float s, float o, float& sm) {
        int lo = A - m;       if (lo < 0)  lo = 0;
        int hi = A + 32 + m;  if (hi > Wd) hi = Wd;
        sm = 0.0f;
        #pragma unroll
        for (int gg = 0; gg < NG; gg++) {
            const int r = lo + gg * 8 + w;
            if (r < hi) {
                const int li = r - rlo;
                const float vcf = ((r > 0) ? 1.0f : 0.0f) + ((r < Wd - 1) ? 1.0f : 0.0f);
                half8 gh = G[gg], eh;
                float local = 0.0f;
                #pragma unroll
                for (int j = 0; j < 8; j++) {
                    const float gv = (float)gh[j];
                    const int col = lane * 8 + j;
                    const float cnt = 1.0f + ((col > 0) ? 1.0f : 0.0f)
                                    + ((col < 511) ? 1.0f : 0.0f) + vcf;
                    float e = fmaxf(0.2f * (s * gv + o * cnt) - 0.5f, 0.0f);
                    _Float16 h = (_Float16)e;
                    eh[j] = h;
                    local += (float)h;
                }
                ((half8*)&tile[li][0])[lane] = eh;
                if (r >= A && r < A + 32) sm += local;
            }
        }
    };

    // ---- passes (LDS-internal, shrinking margins) ----
    #pragma unroll
    for (int p = 0; p < NP; p++) {
        const int m = MIN - 1 - p;
        GATH(m, p == NP - 1, gmnL, gmxL);
        __syncthreads();                   // all reads done before overwrite
        APP(m, scs[2*p], scs[2*p + 1], xsum[p]);
        __syncthreads();                   // writes done before next gather
    }
    if (LA) GATH(0, true, gmnA, gmxA);     // lookahead g~ of our output

    if (WRITE) {
        _Float16* op = out + (size_t)plane * HWp;
        for (int g = tid; g < 32 * W8; g += 512) {
            const int lrow = g >> 6, lcol = g & 63;
            ((half8*)op)[(A + lrow) * W8 + lcol] =
                ((const half8*)&tile[A - rlo + lrow][0])[lcol];
        }
    }

    // ---- reduce + commit ----
    constexpr int NV = 6 + (LA ? 6 : 0) + NP;
    float V[NV];
    #pragma unroll
    for (int c = 0; c < 3; c++) { V[c] = gmnL[c]; V[3 + c] = gmxL[c]; }
    if (LA) {
        #pragma unroll
        for (int c = 0; c < 3; c++) { V[6 + c] = gmnA[c]; V[9 + c] = gmxA[c]; }
    }
    #pragma unroll
    for (int p = 0; p < NP; p++) V[NV - NP + p] = xsum[p];

    for (int off = 32; off > 0; off >>= 1) {
        #pragma unroll
        for (int i = 0; i < NV; i++) {
            float t = __shfl_down(V[i], off);
            const bool mn = (i < 3) || (LA && i >= 6 && i < 9);
            const bool mx = (i >= 3 && i < 6) || (LA && i >= 9 && i < 12);
            if (mn)      V[i] = fminf(V[i], t);
            else if (mx) V[i] = fmaxf(V[i], t);
            else         V[i] += t;
        }
    }
    if (lane == 0) {
        #pragma unroll
        for (int i = 0; i < NV; i++) rsb[w][i] = V[i];
    }
    __syncthreads();
    if (tid == 0) {
        float a[NV];
        for (int i = 0; i < NV; i++) a[i] = rsb[0][i];
        for (int q = 1; q < 8; q++) {
            for (int i = 0; i < NV; i++) {
                const bool mn = (i < 3) || (LA && i >= 6 && i < 9);
                const bool mx = (i >= 3 && i < 6) || (LA && i >= 9 && i < 12);
                if (mn)      a[i] = fminf(a[i], rsb[q][i]);
                else if (mx) a[i] = fmaxf(a[i], rsb[q][i]);
                else         a[i] += rsb[q][i];
            }
        }
        const int slotL = m0 + NP - 1;
        for (int c = 0; c < 3; c++) {
            atomicMax((unsigned*)&red[((slotL-1)*3+c)*32 + plane], ~__float_as_uint(a[c]));
            atomicMax((int*)&red[960 + ((slotL-1)*3+c)*32 + plane], __float_as_int(a[3+c]));
        }
        if (LA) {
            const int slotA = m0 + NP;
            for (int c = 0; c < 3; c++) {
                atomicMax((unsigned*)&red[((slotA-1)*3+c)*32 + plane], ~__float_as_uint(a[6+c]));
                atomicMax((int*)&red[960 + ((slotA-1)*3+c)*32 + plane], __float_as_int(a[9+c]));
            }
        }
        for (int p = 0; p < NP; p++)
            atomicAdd(&red[1920 + (m0 + p - 1) * 32 + plane], a[NV - NP + p]);
    }
}

// One block, 64 threads: walk the (s,o) chain per plane and fold the loss.
__global__ void final_out(const float* __restrict__ red, float* __restrict__ out)
{
    const int lane = threadIdx.x;
    float contrib = 0.0f;
    if (lane < 32) {
        float s = 1.0f, o = 0.0f;
        for (int i = 1; i <= 10; i++) {
            float mn = F_INF, mx = 0.0f;
            #pragma unroll
            for (int c = 0; c < 3; c++) {
                float gn = __uint_as_float(~((const unsigned*)red)[((i-1)*3+c)*32 + lane]);
                float gx = red[960 + ((i-1)*3+c)*32 + lane];
                float cf = (float)(c + 3);
                float emn = (float)(_Float16)fmaxf(0.2f*(s*gn + o*cf) - 0.5f, 0.0f);
                float emx = (float)(_Float16)fmaxf(0.2f*(s*gx + o*cf) - 0.5f, 0.0f);
                mn = fminf(mn, emn);
                mx = fmaxf(mx, emx);
            }
            float denom = mx - mn;
            float ns, no;
            if (denom != 0.0f) { ns = 1.0f / denom; no = -mn / denom; }
            else               { ns = 1.0f;         no = 0.0f; }
            float sm = red[1920 + (i - 1) * 32 + lane];
            contrib += (ns * sm + no * 262144.0f) * (float)(i * i);
            s = ns; o = no;
        }
    }
    for (int off = 16; off > 0; off >>= 1)
        contrib += __shfl_down(contrib, off);
    if (lane == 0) out[0] = contrib / 8388608.0f;
}

extern "C" void kernel_launch(void* const* d_in, const int* in_sizes, int n_in,
                              void* d_out, int out_size, void* d_ws, size_t ws_size,
                              hipStream_t stream)
{
    const float* pred   = (const float*)d_in[0];
    const int*   target = (const int*)d_in[1];
    float* out = (float*)d_out;

    _Float16* h0  = (_Float16*)d_ws;
    _Float16* h1  = h0 + NTOT;
    float*    red = (float*)(h1 + NTOT);

    hipMemsetAsync((void*)red, 0, 2240 * sizeof(float), stream);

    dim3 g(512), b(512);
    // K0: pass 1 (bound from pred/target); commits slots 1 (last) + 2 (LA)
    fusedK<1, true,  true,  true,  2><<<g, b, 0, stream>>>(nullptr, h0, pred, target, red, 1);
    // K1..K3: two passes each + lookahead
    fusedK<2, false, true,  true,  3><<<g, b, 0, stream>>>(h0, h1, nullptr, nullptr, red, 2);
    fusedK<2, false, true,  true,  3><<<g, b, 0, stream>>>(h1, h0, nullptr, nullptr, red, 4);
    fusedK<2, false, true,  true,  3><<<g, b, 0, stream>>>(h0, h1, nullptr, nullptr, red, 6);
    // K4: passes 8,9 (no lookahead needed; K5 commits slot 10 itself)
    fusedK<2, false, false, true,  2><<<g, b, 0, stream>>>(h1, h0, nullptr, nullptr, red, 8);
    // K5: pass 10, stats+sum only, no output buffer
    fusedK<1, false, false, false, 1><<<g, b, 0, stream>>>(h0, nullptr, nullptr, nullptr, red, 10);
    final_out<<<1, 64, 0, stream>>>(red, out);
}